// Round 8
// baseline (770.768 us; speedup 1.0000x reference)
//
#include <hip/hip_runtime.h>
#include <hip/hip_bf16.h>
#include <hip/hip_cooperative_groups.h>

namespace cg = cooperative_groups;

#define N_SRC 50000
#define N_DST 50000
#define N_EDGES 600000
#define IN_FEAT 128
#define OUT_FEAT 128
#define NB 196            // ceil(N_DST/256) scan chunks
#define PREP_BLOCKS 1024  // co-resident with __launch_bounds__(256,4)

typedef __attribute__((ext_vector_type(8))) short short8;   // 8 bf16 = 4 VGPRs
typedef __attribute__((ext_vector_type(4))) float float4v;  // MFMA C/D

#define HS4 (N_SRC * IN_FEAT / 4)          // 1,600,000 float4s
#define HD4 (N_DST * IN_FEAT / 4)          // 1,600,000
#define W4  (OUT_FEAT * 2 * IN_FEAT / 4)   // 8,192
#define CVT_TOTAL (HS4 + HD4 + W4)

// ---------------------------------------------------------------------------
// K_prep (cooperative, ONE dispatch replaces 7):
//   P0: zero deg + f32->bf16 cvt of h_s/h_d/W
//   P1: degree histogram
//   P2: per-chunk exclusive scan (blocks 0..NB-1)
//   P3: scan of chunk totals (block 0)
//   P4: add chunk base -> offsets[] + cursor
//   P5: fill edge permutation
// ---------------------------------------------------------------------------
__global__ __launch_bounds__(256, 4) void prep_kernel(
    const float* __restrict__ h_s, const float* __restrict__ h_d,
    const float* __restrict__ W, ushort* __restrict__ hsb,
    ushort* __restrict__ hdb, ushort* __restrict__ Wbg,
    const int* __restrict__ src, const int* __restrict__ dst,
    int* __restrict__ deg, int* __restrict__ offsets,
    int* __restrict__ bsum, int* __restrict__ boff,
    int* __restrict__ perm)
{
    cg::grid_group grid = cg::this_grid();
    __shared__ int sh[256];

    const int t     = threadIdx.x;
    const int gtid  = blockIdx.x * 256 + t;
    const int gsize = PREP_BLOCKS * 256;

    // ---- P0: zero deg + cvt ----
    for (int i = gtid; i < N_DST; i += gsize) deg[i] = 0;
    for (int idx = gtid; idx < CVT_TOTAL; idx += gsize) {
        const float* in;
        ushort* outp;
        int off;
        if (idx < HS4)            { in = h_s; outp = hsb; off = idx; }
        else if (idx < HS4 + HD4) { in = h_d; outp = hdb; off = idx - HS4; }
        else                      { in = W;   outp = Wbg; off = idx - HS4 - HD4; }
        float4 v = ((const float4*)in)[off];
        __hip_bfloat16 o[4];
        o[0] = __float2bfloat16(v.x);
        o[1] = __float2bfloat16(v.y);
        o[2] = __float2bfloat16(v.z);
        o[3] = __float2bfloat16(v.w);
        *(ushort4*)(outp + (size_t)off * 4) = *(ushort4*)o;
    }
    grid.sync();

    // ---- P1: histogram ----
    for (int e = gtid; e < N_EDGES; e += gsize)
        atomicAdd(&deg[dst[e]], 1);
    grid.sync();

    // ---- P2: per-chunk scan (blocks 0..NB-1, 256 elems each) ----
    if (blockIdx.x < NB) {
        int i = blockIdx.x * 256 + t;
        int v = (i < N_DST) ? deg[i] : 0;
        sh[t] = v;
        __syncthreads();
#pragma unroll
        for (int o = 1; o < 256; o <<= 1) {
            int u = (t >= o) ? sh[t - o] : 0;
            __syncthreads();
            sh[t] += u;
            __syncthreads();
        }
        if (i < N_DST) offsets[i] = sh[t] - v;   // chunk-local exclusive
        if (t == 255) bsum[blockIdx.x] = sh[255];
    }
    grid.sync();

    // ---- P3: scan chunk totals (block 0) ----
    if (blockIdx.x == 0) {
        int v = (t < NB) ? bsum[t] : 0;
        sh[t] = v;
        __syncthreads();
#pragma unroll
        for (int o = 1; o < 256; o <<= 1) {
            int u = (t >= o) ? sh[t - o] : 0;
            __syncthreads();
            sh[t] += u;
            __syncthreads();
        }
        if (t < NB) boff[t] = sh[t] - v;           // exclusive chunk base
        if (t == 255) offsets[N_DST] = sh[255];    // total = N_EDGES
    }
    grid.sync();

    // ---- P4: add chunk base; cursor copy ----
    if (blockIdx.x < NB) {
        int i = blockIdx.x * 256 + t;
        if (i < N_DST) {
            int e2 = offsets[i] + boff[blockIdx.x];
            offsets[i] = e2;
            deg[i]     = e2;   // fill cursor
        }
    }
    grid.sync();

    // ---- P5: fill edge permutation ----
    for (int e = gtid; e < N_EDGES; e += gsize) {
        int d = dst[e];
        int p = atomicAdd(&deg[d], 1);
        perm[p] = src[e];
    }
}

// ---------------------------------------------------------------------------
// K_gather: gather-mean, one wave per dst row, bf16 in -> f32 acc -> bf16 out
// ---------------------------------------------------------------------------
__global__ __launch_bounds__(256) void gather_kernel(
    const ushort* __restrict__ hsb, const int* __restrict__ offsets,
    const int* __restrict__ perm, ushort* __restrict__ neighb)
{
    int wave = threadIdx.x >> 6;
    int lane = threadIdx.x & 63;
    int row  = blockIdx.x * 4 + wave;
    if (row >= N_DST) return;

    int off = offsets[row];
    int end = offsets[row + 1];
    int dg  = end - off;

    float ax = 0.f, ay = 0.f;
    for (int j = off; j < end; j += 8) {
        int   s[8];
        float m[8];
        int s0 = perm[j];
#pragma unroll
        for (int q = 0; q < 8; ++q) {
            bool ok = (j + q < end);
            s[q] = ok ? perm[j + q] : s0;
            m[q] = ok ? 1.f : 0.f;
        }
        ushort2 u[8];
#pragma unroll
        for (int q = 0; q < 8; ++q)
            u[q] = ((const ushort2*)(hsb + (size_t)s[q] * IN_FEAT))[lane];
#pragma unroll
        for (int q = 0; q < 8; ++q) {
            ax += m[q] * __uint_as_float((unsigned)u[q].x << 16);
            ay += m[q] * __uint_as_float((unsigned)u[q].y << 16);
        }
    }
    float inv = (dg > 0) ? (1.0f / (float)dg) : 0.0f;
    __hip_bfloat16 ox = __float2bfloat16(ax * inv);
    __hip_bfloat16 oy = __float2bfloat16(ay * inv);
    ushort2 o = make_ushort2(*(ushort*)&ox, *(ushort*)&oy);
    ((ushort2*)(neighb + (size_t)row * IN_FEAT))[lane] = o;
}

// ---------------------------------------------------------------------------
// K_gemm: MFMA bf16 GEMM with LDS-staged W: out = [hdb | neighb] @ W.T + b
// Block: 256 thr / 4 waves, 128 rows x 128 cols. Wave: 32 rows (2 m-frags).
// W staged fragment-major: frag f=(ks*8+nt) at (f*64+lane)*16 B -> K-loop
// B-reads are lane-contiguous ds_read_b128, conflict-free.
// ---------------------------------------------------------------------------
__global__ __launch_bounds__(256) void gemm_mfma_kernel(
    const ushort* __restrict__ hdb, const ushort* __restrict__ neighb,
    const ushort* __restrict__ Wbg, const float* __restrict__ b,
    float* __restrict__ out)
{
    __shared__ ushort sWb[64 * 64 * 8];   // 64 KB

    int tid  = threadIdx.x;
    int wave = tid >> 6;
    int lane = tid & 63;
    int lm   = lane & 15;
    int lk   = (lane >> 4) * 8;

#pragma unroll
    for (int i = 0; i < 16; ++i) {
        int c  = i * 256 + tid;        // 0..4095 chunk id
        int f  = c >> 6;
        int l  = c & 63;
        int ks = f >> 3;
        int nt = f & 7;
        int row = nt * 16 + (l & 15);
        int col = ks * 32 + (l >> 4) * 8;
        short8 v = *(const short8*)(Wbg + (size_t)row * 256 + col);
        *(short8*)(sWb + (size_t)c * 8) = v;
    }
    __syncthreads();

    int row0 = blockIdx.x * 128 + wave * 32;

    float4v acc0[8], acc1[8];
#pragma unroll
    for (int nt = 0; nt < 8; ++nt) {
        acc0[nt] = (float4v){0.f, 0.f, 0.f, 0.f};
        acc1[nt] = (float4v){0.f, 0.f, 0.f, 0.f};
    }

    int ar0 = row0 + lm;       ar0 = (ar0 < N_DST) ? ar0 : (N_DST - 1);
    int ar1 = row0 + 16 + lm;  ar1 = (ar1 < N_DST) ? ar1 : (N_DST - 1);
    const ushort* a0d = hdb    + (size_t)ar0 * IN_FEAT + lk;
    const ushort* a1d = hdb    + (size_t)ar1 * IN_FEAT + lk;
    const ushort* a0n = neighb + (size_t)ar0 * IN_FEAT + lk;
    const ushort* a1n = neighb + (size_t)ar1 * IN_FEAT + lk;

#pragma unroll
    for (int ks = 0; ks < 8; ++ks) {
        int koff = (ks & 3) * 32;
        short8 af0 = (ks < 4) ? *(const short8*)(a0d + koff)
                              : *(const short8*)(a0n + koff);
        short8 af1 = (ks < 4) ? *(const short8*)(a1d + koff)
                              : *(const short8*)(a1n + koff);
#pragma unroll
        for (int nt = 0; nt < 8; ++nt) {
            short8 bf = *(const short8*)(sWb + ((size_t)(ks * 8 + nt) * 64 + lane) * 8);
            acc0[nt] = __builtin_amdgcn_mfma_f32_16x16x32_bf16(af0, bf, acc0[nt], 0, 0, 0);
            acc1[nt] = __builtin_amdgcn_mfma_f32_16x16x32_bf16(af1, bf, acc1[nt], 0, 0, 0);
        }
    }

    int orow0 = row0 + (lane >> 4) * 4;
#pragma unroll
    for (int nt = 0; nt < 8; ++nt) {
        int col = nt * 16 + lm;
        float bias = b[col];
#pragma unroll
        for (int r = 0; r < 4; ++r) {
            int oa = orow0 + r;
            int ob = oa + 16;
            if (oa < N_DST) out[(size_t)oa * OUT_FEAT + col] = acc0[nt][r] + bias;
            if (ob < N_DST) out[(size_t)ob * OUT_FEAT + col] = acc1[nt][r] + bias;
        }
    }
}

extern "C" void kernel_launch(void* const* d_in, const int* in_sizes, int n_in,
                              void* d_out, int out_size, void* d_ws, size_t ws_size,
                              hipStream_t stream) {
    const float* h_s = (const float*)d_in[0];
    const float* h_d = (const float*)d_in[1];
    const int*   src = (const int*)d_in[2];
    const int*   dst = (const int*)d_in[3];
    const float* W   = (const float*)d_in[4];
    const float* b   = (const float*)d_in[5];
    float* out = (float*)d_out;

    // workspace layout (~41.5 MB)
    int* deg     = (int*)d_ws;                 // N_DST (hist, then cursor)
    int* offsets = deg + N_DST;                // N_DST+1
    int* perm    = offsets + (N_DST + 1);      // N_EDGES
    int* bsum    = perm + N_EDGES;             // NB
    int* boff    = bsum + NB;                  // NB
    int  ihead   = N_DST + (N_DST + 1) + N_EDGES + 2 * NB;
    ihead = (ihead + 3) & ~3;                  // 16 B align
    ushort* hsb    = (ushort*)((int*)d_ws + ihead);       // N_SRC*128 bf16
    ushort* hdb    = hsb + (size_t)N_SRC * IN_FEAT;       // N_DST*128 bf16
    ushort* neighb = hdb + (size_t)N_DST * IN_FEAT;       // N_DST*128 bf16
    ushort* Wbg    = neighb + (size_t)N_DST * IN_FEAT;    // 128*256 bf16

    void* args[] = {
        (void*)&h_s, (void*)&h_d, (void*)&W, (void*)&hsb, (void*)&hdb,
        (void*)&Wbg, (void*)&src, (void*)&dst, (void*)&deg, (void*)&offsets,
        (void*)&bsum, (void*)&boff, (void*)&perm
    };
    hipLaunchCooperativeKernel((void*)prep_kernel, dim3(PREP_BLOCKS), dim3(256),
                               args, 0, stream);

    gather_kernel<<<(N_DST + 3) / 4, 256, 0, stream>>>(
        hsb, offsets, perm, neighb);
    gemm_mfma_kernel<<<(N_DST + 127) / 128, 256, 0, stream>>>(
        hdb, neighb, Wbg, b, out);
}

// Round 9
// 195.465 us; speedup vs baseline: 3.9433x; 3.9433x over previous
//
#include <hip/hip_runtime.h>
#include <hip/hip_bf16.h>

#define N_SRC 50000
#define N_DST 50000
#define N_EDGES 600000
#define IN_FEAT 128
#define OUT_FEAT 128
#define CAP 128                         // per-dst bucket capacity (Poisson(12))

typedef __attribute__((ext_vector_type(8))) short short8;   // 8 bf16 = 4 VGPRs
typedef __attribute__((ext_vector_type(4))) float float4v;  // MFMA C/D

#define HS4 (N_SRC * IN_FEAT / 4)       // 1,600,000 float4s
#define CVT_BLOCKS (HS4 / 256)          // 6250
#define FILL_BLOCKS ((N_EDGES + 255) / 256)   // 2344

// ---------------------------------------------------------------------------
// K1 (split-grid fusion of two independent jobs):
//   blocks [0, CVT_BLOCKS):              f32->bf16 convert h_s
//   blocks [CVT_BLOCKS, +FILL_BLOCKS):   bucket-fill perm (deg = cursor+count)
// No scan needed: perm[d*CAP + slot] with slot from atomicAdd(deg[d],1).
// ---------------------------------------------------------------------------
__global__ __launch_bounds__(256) void cvtfill_kernel(
    const float* __restrict__ h_s, ushort* __restrict__ hsb,
    const int* __restrict__ src, const int* __restrict__ dst,
    int* __restrict__ deg, int* __restrict__ perm)
{
    int bid = blockIdx.x;
    if (bid < CVT_BLOCKS) {
        int idx = bid * 256 + threadIdx.x;
        float4 v = ((const float4*)h_s)[idx];
        __hip_bfloat16 o[4];
        o[0] = __float2bfloat16(v.x);
        o[1] = __float2bfloat16(v.y);
        o[2] = __float2bfloat16(v.z);
        o[3] = __float2bfloat16(v.w);
        *(ushort4*)(hsb + (size_t)idx * 4) = *(ushort4*)o;
    } else {
        int e = (bid - CVT_BLOCKS) * 256 + threadIdx.x;
        if (e < N_EDGES) {
            int d = dst[e];
            int p = atomicAdd(&deg[d], 1);
            perm[d * CAP + p] = src[e];
        }
    }
}

// ---------------------------------------------------------------------------
// K2: gather-mean, one wave per dst row, bf16 in -> f32 acc -> bf16 out.
// Bucketed perm: row's edges at perm[row*CAP .. +deg[row]).
// ---------------------------------------------------------------------------
__global__ __launch_bounds__(256) void gather_kernel(
    const ushort* __restrict__ hsb, const int* __restrict__ deg,
    const int* __restrict__ perm, ushort* __restrict__ neighb)
{
    int wave = threadIdx.x >> 6;
    int lane = threadIdx.x & 63;
    int row  = blockIdx.x * 4 + wave;
    if (row >= N_DST) return;

    int dg  = deg[row];
    int off = row * CAP;
    int end = off + dg;

    float ax = 0.f, ay = 0.f;
    for (int j = off; j < end; j += 8) {
        int   s[8];
        float m[8];
        int s0 = perm[j];
#pragma unroll
        for (int q = 0; q < 8; ++q) {
            bool ok = (j + q < end);
            s[q] = ok ? perm[j + q] : s0;
            m[q] = ok ? 1.f : 0.f;
        }
        ushort2 u[8];
#pragma unroll
        for (int q = 0; q < 8; ++q)
            u[q] = ((const ushort2*)(hsb + (size_t)s[q] * IN_FEAT))[lane];
#pragma unroll
        for (int q = 0; q < 8; ++q) {
            ax += m[q] * __uint_as_float((unsigned)u[q].x << 16);
            ay += m[q] * __uint_as_float((unsigned)u[q].y << 16);
        }
    }
    float inv = (dg > 0) ? (1.0f / (float)dg) : 0.0f;
    __hip_bfloat16 ox = __float2bfloat16(ax * inv);
    __hip_bfloat16 oy = __float2bfloat16(ay * inv);
    ushort2 o = make_ushort2(*(ushort*)&ox, *(ushort*)&oy);
    ((ushort2*)(neighb + (size_t)row * IN_FEAT))[lane] = o;
}

// ---------------------------------------------------------------------------
// K3: MFMA bf16 GEMM, W and h_d converted in-kernel from f32:
//   out = [bf16(h_d) | neighb] @ bf16(W).T + b
// Block: 256 thr / 4 waves, 128 rows x 128 cols. Wave: 32 rows (2 m-frags).
// W staged fragment-major in LDS (cvt f32->bf16 while staging): frag
// f=(ks*8+nt) chunk at (f*64+lane)*16 B -> conflict-free ds_read_b128.
// A-frags for ks<4 load 2x float4 from h_d f32 and cvt in-register.
// ---------------------------------------------------------------------------
__global__ __launch_bounds__(256) void gemm_mfma_kernel(
    const float* __restrict__ h_d, const ushort* __restrict__ neighb,
    const float* __restrict__ W, const float* __restrict__ b,
    float* __restrict__ out)
{
    __shared__ ushort sWb[64 * 64 * 8];   // 64 KB

    int tid  = threadIdx.x;
    int wave = tid >> 6;
    int lane = tid & 63;
    int lm   = lane & 15;
    int lk   = (lane >> 4) * 8;

    // ---- stage W (f32 global) into LDS as bf16, fragment-major ----
#pragma unroll
    for (int i = 0; i < 16; ++i) {
        int c  = i * 256 + tid;        // 0..4095 chunk id (8 bf16 each)
        int f  = c >> 6;
        int l  = c & 63;
        int ks = f >> 3;
        int nt = f & 7;
        int row = nt * 16 + (l & 15);
        int col = ks * 32 + (l >> 4) * 8;
        const float* wp = W + (size_t)row * 256 + col;
        float4 w0 = *(const float4*)(wp);
        float4 w1 = *(const float4*)(wp + 4);
        __hip_bfloat16 o[8];
        o[0] = __float2bfloat16(w0.x); o[1] = __float2bfloat16(w0.y);
        o[2] = __float2bfloat16(w0.z); o[3] = __float2bfloat16(w0.w);
        o[4] = __float2bfloat16(w1.x); o[5] = __float2bfloat16(w1.y);
        o[6] = __float2bfloat16(w1.z); o[7] = __float2bfloat16(w1.w);
        *(short8*)(sWb + (size_t)c * 8) = *(short8*)o;
    }
    __syncthreads();

    int row0 = blockIdx.x * 128 + wave * 32;

    float4v acc0[8], acc1[8];
#pragma unroll
    for (int nt = 0; nt < 8; ++nt) {
        acc0[nt] = (float4v){0.f, 0.f, 0.f, 0.f};
        acc1[nt] = (float4v){0.f, 0.f, 0.f, 0.f};
    }

    int ar0 = row0 + lm;       ar0 = (ar0 < N_DST) ? ar0 : (N_DST - 1);
    int ar1 = row0 + 16 + lm;  ar1 = (ar1 < N_DST) ? ar1 : (N_DST - 1);
    const float*  a0d = h_d    + (size_t)ar0 * IN_FEAT + lk;
    const float*  a1d = h_d    + (size_t)ar1 * IN_FEAT + lk;
    const ushort* a0n = neighb + (size_t)ar0 * IN_FEAT + lk;
    const ushort* a1n = neighb + (size_t)ar1 * IN_FEAT + lk;

#pragma unroll
    for (int ks = 0; ks < 8; ++ks) {
        int koff = (ks & 3) * 32;
        short8 af0, af1;
        if (ks < 4) {
            float4 p0 = *(const float4*)(a0d + koff);
            float4 p1 = *(const float4*)(a0d + koff + 4);
            float4 q0 = *(const float4*)(a1d + koff);
            float4 q1 = *(const float4*)(a1d + koff + 4);
            __hip_bfloat16 oa[8], ob[8];
            oa[0] = __float2bfloat16(p0.x); oa[1] = __float2bfloat16(p0.y);
            oa[2] = __float2bfloat16(p0.z); oa[3] = __float2bfloat16(p0.w);
            oa[4] = __float2bfloat16(p1.x); oa[5] = __float2bfloat16(p1.y);
            oa[6] = __float2bfloat16(p1.z); oa[7] = __float2bfloat16(p1.w);
            ob[0] = __float2bfloat16(q0.x); ob[1] = __float2bfloat16(q0.y);
            ob[2] = __float2bfloat16(q0.z); ob[3] = __float2bfloat16(q0.w);
            ob[4] = __float2bfloat16(q1.x); ob[5] = __float2bfloat16(q1.y);
            ob[6] = __float2bfloat16(q1.z); ob[7] = __float2bfloat16(q1.w);
            af0 = *(short8*)oa;
            af1 = *(short8*)ob;
        } else {
            af0 = *(const short8*)(a0n + koff);
            af1 = *(const short8*)(a1n + koff);
        }
#pragma unroll
        for (int nt = 0; nt < 8; ++nt) {
            short8 bf = *(const short8*)(sWb + ((size_t)(ks * 8 + nt) * 64 + lane) * 8);
            acc0[nt] = __builtin_amdgcn_mfma_f32_16x16x32_bf16(af0, bf, acc0[nt], 0, 0, 0);
            acc1[nt] = __builtin_amdgcn_mfma_f32_16x16x32_bf16(af1, bf, acc1[nt], 0, 0, 0);
        }
    }

    // ---- epilogue: C/D layout col=lane&15, row=(lane>>4)*4+reg ----
    int orow0 = row0 + (lane >> 4) * 4;
#pragma unroll
    for (int nt = 0; nt < 8; ++nt) {
        int col = nt * 16 + lm;
        float bias = b[col];
#pragma unroll
        for (int r = 0; r < 4; ++r) {
            int oa = orow0 + r;
            int ob = oa + 16;
            if (oa < N_DST) out[(size_t)oa * OUT_FEAT + col] = acc0[nt][r] + bias;
            if (ob < N_DST) out[(size_t)ob * OUT_FEAT + col] = acc1[nt][r] + bias;
        }
    }
}

extern "C" void kernel_launch(void* const* d_in, const int* in_sizes, int n_in,
                              void* d_out, int out_size, void* d_ws, size_t ws_size,
                              hipStream_t stream) {
    const float* h_s = (const float*)d_in[0];
    const float* h_d = (const float*)d_in[1];
    const int*   src = (const int*)d_in[2];
    const int*   dst = (const int*)d_in[3];
    const float* W   = (const float*)d_in[4];
    const float* b   = (const float*)d_in[5];
    float* out = (float*)d_out;

    // workspace layout (~51.5 MB of the 256 MiB ws)
    int* deg  = (int*)d_ws;                      // N_DST (cursor -> degree)
    int* perm = deg + N_DST;                     // N_DST * CAP
    ushort* hsb    = (ushort*)(perm + (size_t)N_DST * CAP);  // N_SRC*128 bf16
    ushort* neighb = hsb + (size_t)N_SRC * IN_FEAT;          // N_DST*128 bf16

    hipMemsetAsync(deg, 0, N_DST * sizeof(int), stream);

    cvtfill_kernel<<<CVT_BLOCKS + FILL_BLOCKS, 256, 0, stream>>>(
        h_s, hsb, src, dst, deg, perm);
    gather_kernel<<<(N_DST + 3) / 4, 256, 0, stream>>>(
        hsb, deg, perm, neighb);
    gemm_mfma_kernel<<<(N_DST + 127) / 128, 256, 0, stream>>>(
        h_d, neighb, W, b, out);
}